// Round 3
// baseline (649.865 us; speedup 1.0000x reference)
//
#include <hip/hip_runtime.h>

typedef _Float16 half2_t __attribute__((ext_vector_type(2)));
typedef _Float16 half4_t __attribute__((ext_vector_type(4)));
typedef _Float16 half8_t __attribute__((ext_vector_type(8)));
typedef __fp16   fp16x2  __attribute__((ext_vector_type(2)));
typedef float    f32x4   __attribute__((ext_vector_type(4)));

#define BS 128
#define DH 64

__device__ __forceinline__ half2_t pkrtz(float x, float y) {
  fp16x2 t = __builtin_amdgcn_cvt_pkrtz(x, y);
  return __builtin_bit_cast(half2_t, t);
}

__device__ __forceinline__ half8_t cvt8(const float4 a, const float4 b) {
  half2_t h0 = pkrtz(a.x, a.y);
  half2_t h1 = pkrtz(a.z, a.w);
  half2_t h2 = pkrtz(b.x, b.y);
  half2_t h3 = pkrtz(b.z, b.w);
  half4_t lo = __builtin_shufflevector(h0, h1, 0, 1, 2, 3);
  half4_t hi = __builtin_shufflevector(h2, h3, 0, 1, 2, 3);
  return __builtin_shufflevector(lo, hi, 0, 1, 2, 3, 4, 5, 6, 7);
}

__global__ __launch_bounds__(256, 5) void ball_attn_kernel(
    const float* __restrict__ Q, const float* __restrict__ Kk,
    const float* __restrict__ V, float* __restrict__ O) {
  // 16 KB + 16 KB = 32 KB exactly -> 5 blocks/CU. XOR-swizzled, no pad.
  __shared__ __align__(16) _Float16 VT[DH][BS];     // [d][key]
  __shared__ __align__(16) _Float16 Pl[4][16][BS];  // per-wave P half-tile

  const int tid  = threadIdx.x;
  const int w    = tid >> 6;   // wave 0..3, owns q rows [32w, 32w+32)
  const int lane = tid & 63;
  const int c    = lane & 15;
  const int g    = lane >> 4;

  const size_t base = (size_t)blockIdx.x * (BS * DH);
  const float* Qb = Q + base;
  const float* Kb = Kk + base;
  const float* Vb = V + base;
  float*       Ob = O + base;

  // ---- issue ALL first-touch global loads back-to-back (one round trip) ----
  // V: thread covers keys {2kp, 2kp+1} at d0..d0+3, 4 iterations
  const int kp0 = tid >> 4;        // 0..15
  const int d0  = (tid & 15) * 4;  // 0..60
  float4 vA[4], vB[4];
#pragma unroll
  for (int it = 0; it < 4; ++it) {
    const int key0 = 2 * (it * 16 + kp0);
    vA[it] = *(const float4*)(Vb + (size_t)key0 * DH + d0);
    vB[it] = *(const float4*)(Vb + (size_t)(key0 + 1) * DH + d0);
  }
  // Q (unscaled; scale folded into exp argument later)
  float4 qraw[2][2][2];
#pragma unroll
  for (int m = 0; m < 2; ++m)
#pragma unroll
    for (int ks = 0; ks < 2; ++ks) {
      const float* qp = Qb + (w * 32 + m * 16 + c) * DH + ks * 32 + g * 8;
      qraw[m][ks][0] = *(const float4*)qp;
      qraw[m][ks][1] = *(const float4*)(qp + 4);
    }
  // K kt=0 prefetch
  float4 kraw[2][2];
#pragma unroll
  for (int ks = 0; ks < 2; ++ks) {
    const float* kp = Kb + c * DH + ks * 32 + g * 8;
    kraw[ks][0] = *(const float4*)kp;
    kraw[ks][1] = *(const float4*)(kp + 4);
  }

  // ---- convert + stage V^T (half2 writes along key), swizzled ----
#pragma unroll
  for (int it = 0; it < 4; ++it) {
    const int key0 = 2 * (it * 16 + kp0);
    const float* a = (const float*)&vA[it];
    const float* b = (const float*)&vB[it];
#pragma unroll
    for (int j = 0; j < 4; ++j) {
      const int d = d0 + j;
      half2_t h = pkrtz(a[j], b[j]);
      *(half2_t*)&VT[d][key0 ^ ((d & 7) << 3)] = h;
    }
  }
  // ---- convert Q ----
  half8_t aq[2][2];
#pragma unroll
  for (int m = 0; m < 2; ++m)
#pragma unroll
    for (int ks = 0; ks < 2; ++ks)
      aq[m][ks] = cvt8(qraw[m][ks][0], qraw[m][ks][1]);

  __syncthreads();  // VT visible to all waves (only barrier in the kernel)

  // ---- per 16-row half: QK^T -> softmax -> P|LDS -> PV -> store ----
#pragma unroll
  for (int m = 0; m < 2; ++m) {
    f32x4 acc[8];
#pragma unroll
    for (int kt = 0; kt < 8; ++kt) acc[kt] = (f32x4){0.f, 0.f, 0.f, 0.f};

#pragma unroll
    for (int kt = 0; kt < 8; ++kt)
#pragma unroll
      for (int ks = 0; ks < 2; ++ks) {
        half8_t bk;
        if (m == 0 && kt == 0) {
          bk = cvt8(kraw[ks][0], kraw[ks][1]);
        } else {
          const float* kp = Kb + (kt * 16 + c) * DH + ks * 32 + g * 8;
          bk = cvt8(*(const float4*)kp, *(const float4*)(kp + 4));
        }
        acc[kt] = __builtin_amdgcn_mfma_f32_16x16x32_f16(aq[m][ks], bk, acc[kt], 0, 0, 0);
      }

    // softmax over cols kt*16+c; lane holds rows 4g+r (within this 16-half)
    float mx[4], sm[4], inv[4];
#pragma unroll
    for (int r = 0; r < 4; ++r) {
      mx[r] = acc[0][r];
#pragma unroll
      for (int kt = 1; kt < 8; ++kt) mx[r] = fmaxf(mx[r], acc[kt][r]);
    }
#pragma unroll
    for (int r = 0; r < 4; ++r) {
      mx[r] = fmaxf(mx[r], __shfl_xor(mx[r], 1));
      mx[r] = fmaxf(mx[r], __shfl_xor(mx[r], 2));
      mx[r] = fmaxf(mx[r], __shfl_xor(mx[r], 4));
      mx[r] = fmaxf(mx[r], __shfl_xor(mx[r], 8));
      sm[r] = 0.f;
    }
#pragma unroll
    for (int kt = 0; kt < 8; ++kt)
#pragma unroll
      for (int r = 0; r < 4; ++r) {
        const float p = __expf((acc[kt][r] - mx[r]) * 0.125f);
        acc[kt][r] = p;
        sm[r] += p;
      }
#pragma unroll
    for (int r = 0; r < 4; ++r) {
      sm[r] += __shfl_xor(sm[r], 1);
      sm[r] += __shfl_xor(sm[r], 2);
      sm[r] += __shfl_xor(sm[r], 4);
      sm[r] += __shfl_xor(sm[r], 8);
      inv[r] = __builtin_amdgcn_rcpf(sm[r]);  // sum >= 1, safe
    }
    // write P (f16) swizzled; same-wave LDS is ordered -> no barrier
#pragma unroll
    for (int kt = 0; kt < 8; ++kt)
#pragma unroll
      for (int r = 0; r < 4; ++r) {
        const int row = 4 * g + r;
        Pl[w][row][(kt * 16 + c) ^ ((row & 7) << 3)] = (_Float16)acc[kt][r];
      }

    // PV: A = P row c (key-contig), B = VT row d (key-contig)
    f32x4 o[4];
#pragma unroll
    for (int t = 0; t < 4; ++t) o[t] = (f32x4){0.f, 0.f, 0.f, 0.f};
#pragma unroll
    for (int ks = 0; ks < 4; ++ks) {
      const int e = (ks * 32 + g * 8) ^ ((c & 7) << 3);  // same swizzle, rows c / t*16+c
      const half8_t pf = *(const half8_t*)&Pl[w][c][e];
#pragma unroll
      for (int t = 0; t < 4; ++t) {
        const half8_t vf = *(const half8_t*)&VT[t * 16 + c][e];
        o[t] = __builtin_amdgcn_mfma_f32_16x16x32_f16(pf, vf, o[t], 0, 0, 0);
      }
    }
    // store (rows 4g+r, cols t*16+c), scaled by 1/rowsum
#pragma unroll
    for (int t = 0; t < 4; ++t)
#pragma unroll
      for (int r = 0; r < 4; ++r)
        Ob[(w * 32 + m * 16 + 4 * g + r) * DH + t * 16 + c] = o[t][r] * inv[r];
  }
}

extern "C" void kernel_launch(void* const* d_in, const int* in_sizes, int n_in,
                              void* d_out, int out_size, void* d_ws, size_t ws_size,
                              hipStream_t stream) {
  const float* q = (const float*)d_in[0];
  const float* k = (const float*)d_in[1];
  const float* v = (const float*)d_in[2];
  float* out = (float*)d_out;
  const int nballs = in_sizes[0] / (BS * DH);  // 4096
  ball_attn_kernel<<<dim3(nballs), dim3(256), 0, stream>>>(q, k, v, out);
}

// Round 4
// 609.673 us; speedup vs baseline: 1.0659x; 1.0659x over previous
//
#include <hip/hip_runtime.h>

typedef _Float16 half2_t __attribute__((ext_vector_type(2)));
typedef _Float16 half4_t __attribute__((ext_vector_type(4)));
typedef _Float16 half8_t __attribute__((ext_vector_type(8)));
typedef __fp16   fp16x2  __attribute__((ext_vector_type(2)));
typedef float    f32x4   __attribute__((ext_vector_type(4)));

#define BS 128
#define DH 64

__device__ __forceinline__ half2_t pkrtz(float x, float y) {
  fp16x2 t = __builtin_amdgcn_cvt_pkrtz(x, y);
  return __builtin_bit_cast(half2_t, t);
}

__device__ __forceinline__ half8_t cvt8(const float4 a, const float4 b) {
  half2_t h0 = pkrtz(a.x, a.y);
  half2_t h1 = pkrtz(a.z, a.w);
  half2_t h2 = pkrtz(b.x, b.y);
  half2_t h3 = pkrtz(b.z, b.w);
  half4_t lo = __builtin_shufflevector(h0, h1, 0, 1, 2, 3);
  half4_t hi = __builtin_shufflevector(h2, h3, 0, 1, 2, 3);
  return __builtin_shufflevector(lo, hi, 0, 1, 2, 3, 4, 5, 6, 7);
}

__global__ __launch_bounds__(256, 5) void ball_attn_kernel(
    const float* __restrict__ Q, const float* __restrict__ Kk,
    const float* __restrict__ V, float* __restrict__ O) {
  // 16 KB + 16 KB = 32 KB -> 5 blocks/CU (LDS-limited). XOR-swizzled, no pad.
  __shared__ __align__(16) _Float16 VT[DH][BS];     // [d][key]
  __shared__ __align__(16) _Float16 Pl[4][16][BS];  // per-wave P half-tile

  const int tid  = threadIdx.x;
  const int w    = tid >> 6;   // wave 0..3, owns q rows [32w, 32w+32)
  const int lane = tid & 63;
  const int c    = lane & 15;
  const int g    = lane >> 4;

  const size_t base = (size_t)blockIdx.x * (BS * DH);
  const float* Qb = Q + base;
  const float* Kb = Kk + base;
  const float* Vb = V + base;
  float*       Ob = O + base;

  // ---- stage V^T: STREAMING load->cvt->write (2 float4 live at a time) ----
  {
    const int kp0 = tid >> 4;        // 0..15
    const int d0  = (tid & 15) * 4;  // 0..60
#pragma unroll
    for (int it = 0; it < 4; ++it) {
      const int key0 = 2 * (it * 16 + kp0);
      const float4 a = *(const float4*)(Vb + (size_t)key0 * DH + d0);
      const float4 b = *(const float4*)(Vb + (size_t)(key0 + 1) * DH + d0);
      const float* ap = (const float*)&a;
      const float* bp = (const float*)&b;
#pragma unroll
      for (int j = 0; j < 4; ++j) {
        const int d = d0 + j;
        *(half2_t*)&VT[d][key0 ^ ((d & 7) << 3)] = pkrtz(ap[j], bp[j]);
      }
    }
  }

  // ---- Q fragments: load -> convert immediately (2 float4 live) ----
  half8_t aq[2][2];
#pragma unroll
  for (int m = 0; m < 2; ++m)
#pragma unroll
    for (int ks = 0; ks < 2; ++ks) {
      const float* qp = Qb + (w * 32 + m * 16 + c) * DH + ks * 32 + g * 8;
      aq[m][ks] = cvt8(*(const float4*)qp, *(const float4*)(qp + 4));
    }

  __syncthreads();  // VT visible to all waves (only barrier in the kernel)

  // ---- per 16-row half: QK^T -> softmax -> P|LDS -> PV -> store ----
#pragma unroll
  for (int m = 0; m < 2; ++m) {
    f32x4 acc[8];
#pragma unroll
    for (int kt = 0; kt < 8; ++kt) acc[kt] = (f32x4){0.f, 0.f, 0.f, 0.f};

#pragma unroll
    for (int kt = 0; kt < 8; ++kt)
#pragma unroll
      for (int ks = 0; ks < 2; ++ks) {
        const float* kp = Kb + (kt * 16 + c) * DH + ks * 32 + g * 8;
        const half8_t bk = cvt8(*(const float4*)kp, *(const float4*)(kp + 4));
        acc[kt] = __builtin_amdgcn_mfma_f32_16x16x32_f16(aq[m][ks], bk, acc[kt], 0, 0, 0);
      }

    // softmax over cols kt*16+c; lane holds rows 4g+r (within this 16-half)
    float mx[4], sm[4], inv[4];
#pragma unroll
    for (int r = 0; r < 4; ++r) {
      mx[r] = acc[0][r];
#pragma unroll
      for (int kt = 1; kt < 8; ++kt) mx[r] = fmaxf(mx[r], acc[kt][r]);
    }
#pragma unroll
    for (int r = 0; r < 4; ++r) {
      mx[r] = fmaxf(mx[r], __shfl_xor(mx[r], 1));
      mx[r] = fmaxf(mx[r], __shfl_xor(mx[r], 2));
      mx[r] = fmaxf(mx[r], __shfl_xor(mx[r], 4));
      mx[r] = fmaxf(mx[r], __shfl_xor(mx[r], 8));
      sm[r] = 0.f;
    }
#pragma unroll
    for (int kt = 0; kt < 8; ++kt)
#pragma unroll
      for (int r = 0; r < 4; ++r) {
        const float p = __expf((acc[kt][r] - mx[r]) * 0.125f);
        acc[kt][r] = p;
        sm[r] += p;
      }
#pragma unroll
    for (int r = 0; r < 4; ++r) {
      sm[r] += __shfl_xor(sm[r], 1);
      sm[r] += __shfl_xor(sm[r], 2);
      sm[r] += __shfl_xor(sm[r], 4);
      sm[r] += __shfl_xor(sm[r], 8);
      inv[r] = __builtin_amdgcn_rcpf(sm[r]);  // sum >= 1, safe
    }
    // write P (f16) swizzled; same-wave LDS is ordered -> no barrier needed
#pragma unroll
    for (int kt = 0; kt < 8; ++kt)
#pragma unroll
      for (int r = 0; r < 4; ++r) {
        const int row = 4 * g + r;
        Pl[w][row][(kt * 16 + c) ^ ((row & 7) << 3)] = (_Float16)acc[kt][r];
      }

    // PV: A = P row c (key-contig), B = VT row d (key-contig)
    f32x4 o[4];
#pragma unroll
    for (int t = 0; t < 4; ++t) o[t] = (f32x4){0.f, 0.f, 0.f, 0.f};
#pragma unroll
    for (int ks = 0; ks < 4; ++ks) {
      const int e = (ks * 32 + g * 8) ^ ((c & 7) << 3);  // matching swizzle
      const half8_t pf = *(const half8_t*)&Pl[w][c][e];
#pragma unroll
      for (int t = 0; t < 4; ++t) {
        const half8_t vf = *(const half8_t*)&VT[t * 16 + c][e];
        o[t] = __builtin_amdgcn_mfma_f32_16x16x32_f16(pf, vf, o[t], 0, 0, 0);
      }
    }
    // store (rows 4g+r, cols t*16+c), scaled by 1/rowsum
#pragma unroll
    for (int t = 0; t < 4; ++t)
#pragma unroll
      for (int r = 0; r < 4; ++r)
        Ob[(w * 32 + m * 16 + 4 * g + r) * DH + t * 16 + c] = o[t][r] * inv[r];
  }
}

extern "C" void kernel_launch(void* const* d_in, const int* in_sizes, int n_in,
                              void* d_out, int out_size, void* d_ws, size_t ws_size,
                              hipStream_t stream) {
  const float* q = (const float*)d_in[0];
  const float* k = (const float*)d_in[1];
  const float* v = (const float*)d_in[2];
  float* out = (float*)d_out;
  const int nballs = in_sizes[0] / (BS * DH);  // 4096
  ball_attn_kernel<<<dim3(nballs), dim3(256), 0, stream>>>(q, k, v, out);
}

// Round 5
// 530.258 us; speedup vs baseline: 1.2256x; 1.1498x over previous
//
#include <hip/hip_runtime.h>

typedef _Float16 half2_t __attribute__((ext_vector_type(2)));
typedef _Float16 half4_t __attribute__((ext_vector_type(4)));
typedef _Float16 half8_t __attribute__((ext_vector_type(8)));
typedef __fp16   fp16x2  __attribute__((ext_vector_type(2)));
typedef float    f32x4   __attribute__((ext_vector_type(4)));

#define BS 128
#define DH 64

__device__ __forceinline__ half2_t pkrtz(float x, float y) {
  fp16x2 t = __builtin_amdgcn_cvt_pkrtz(x, y);
  return __builtin_bit_cast(half2_t, t);
}

__device__ __forceinline__ half8_t cvt8(const float4 a, const float4 b) {
  half2_t h0 = pkrtz(a.x, a.y);
  half2_t h1 = pkrtz(a.z, a.w);
  half2_t h2 = pkrtz(b.x, b.y);
  half2_t h3 = pkrtz(b.z, b.w);
  half4_t lo = __builtin_shufflevector(h0, h1, 0, 1, 2, 3);
  half4_t hi = __builtin_shufflevector(h2, h3, 0, 1, 2, 3);
  return __builtin_shufflevector(lo, hi, 0, 1, 2, 3, 4, 5, 6, 7);
}

__global__ __launch_bounds__(256, 4) void ball_attn_kernel(
    const float* __restrict__ Q, const float* __restrict__ Kk,
    const float* __restrict__ V, float* __restrict__ O) {
  // 16 KB + 16 KB = 32 KB. XOR-swizzled, no pad.
  // (256,4): 4 waves/SIMD -> VGPR cap 128; streaming demand ~95 fits, no spill.
  __shared__ __align__(16) _Float16 VT[DH][BS];     // [d][key]
  __shared__ __align__(16) _Float16 Pl[4][16][BS];  // per-wave P half-tile

  const int tid  = threadIdx.x;
  const int w    = tid >> 6;   // wave 0..3, owns q rows [32w, 32w+32)
  const int lane = tid & 63;
  const int c    = lane & 15;
  const int g    = lane >> 4;

  const size_t base = (size_t)blockIdx.x * (BS * DH);
  const float* Qb = Q + base;
  const float* Kb = Kk + base;
  const float* Vb = V + base;
  float*       Ob = O + base;

  // ---- stage V^T: STREAMING load->cvt->write (2 float4 live at a time) ----
  {
    const int kp0 = tid >> 4;        // 0..15
    const int d0  = (tid & 15) * 4;  // 0..60
#pragma unroll
    for (int it = 0; it < 4; ++it) {
      const int key0 = 2 * (it * 16 + kp0);
      const float4 a = *(const float4*)(Vb + (size_t)key0 * DH + d0);
      const float4 b = *(const float4*)(Vb + (size_t)(key0 + 1) * DH + d0);
      const float* ap = (const float*)&a;
      const float* bp = (const float*)&b;
#pragma unroll
      for (int j = 0; j < 4; ++j) {
        const int d = d0 + j;
        *(half2_t*)&VT[d][key0 ^ ((d & 7) << 3)] = pkrtz(ap[j], bp[j]);
      }
    }
  }

  // ---- Q fragments: load -> convert immediately (2 float4 live) ----
  half8_t aq[2][2];
#pragma unroll
  for (int m = 0; m < 2; ++m)
#pragma unroll
    for (int ks = 0; ks < 2; ++ks) {
      const float* qp = Qb + (w * 32 + m * 16 + c) * DH + ks * 32 + g * 8;
      aq[m][ks] = cvt8(*(const float4*)qp, *(const float4*)(qp + 4));
    }

  __syncthreads();  // VT visible to all waves (only barrier in the kernel)

  // ---- per 16-row half: QK^T -> softmax -> P|LDS -> PV -> store ----
#pragma unroll
  for (int m = 0; m < 2; ++m) {
    f32x4 acc[8];
#pragma unroll
    for (int kt = 0; kt < 8; ++kt) acc[kt] = (f32x4){0.f, 0.f, 0.f, 0.f};

#pragma unroll
    for (int kt = 0; kt < 8; ++kt)
#pragma unroll
      for (int ks = 0; ks < 2; ++ks) {
        const float* kp = Kb + (kt * 16 + c) * DH + ks * 32 + g * 8;
        const half8_t bk = cvt8(*(const float4*)kp, *(const float4*)(kp + 4));
        acc[kt] = __builtin_amdgcn_mfma_f32_16x16x32_f16(aq[m][ks], bk, acc[kt], 0, 0, 0);
      }

    // softmax over cols kt*16+c; lane holds rows 4g+r (within this 16-half)
    float mx[4], sm[4], inv[4];
#pragma unroll
    for (int r = 0; r < 4; ++r) {
      mx[r] = acc[0][r];
#pragma unroll
      for (int kt = 1; kt < 8; ++kt) mx[r] = fmaxf(mx[r], acc[kt][r]);
    }
#pragma unroll
    for (int r = 0; r < 4; ++r) {
      mx[r] = fmaxf(mx[r], __shfl_xor(mx[r], 1));
      mx[r] = fmaxf(mx[r], __shfl_xor(mx[r], 2));
      mx[r] = fmaxf(mx[r], __shfl_xor(mx[r], 4));
      mx[r] = fmaxf(mx[r], __shfl_xor(mx[r], 8));
      sm[r] = 0.f;
    }
#pragma unroll
    for (int kt = 0; kt < 8; ++kt)
#pragma unroll
      for (int r = 0; r < 4; ++r) {
        const float p = __expf((acc[kt][r] - mx[r]) * 0.125f);
        acc[kt][r] = p;
        sm[r] += p;
      }
#pragma unroll
    for (int r = 0; r < 4; ++r) {
      sm[r] += __shfl_xor(sm[r], 1);
      sm[r] += __shfl_xor(sm[r], 2);
      sm[r] += __shfl_xor(sm[r], 4);
      sm[r] += __shfl_xor(sm[r], 8);
      inv[r] = __builtin_amdgcn_rcpf(sm[r]);  // sum >= 1, safe
    }
    // write P (f16) swizzled; same-wave LDS is ordered -> no barrier needed
#pragma unroll
    for (int kt = 0; kt < 8; ++kt)
#pragma unroll
      for (int r = 0; r < 4; ++r) {
        const int row = 4 * g + r;
        Pl[w][row][(kt * 16 + c) ^ ((row & 7) << 3)] = (_Float16)acc[kt][r];
      }

    // PV: A = P row c (key-contig), B = VT row d (key-contig)
    f32x4 o[4];
#pragma unroll
    for (int t = 0; t < 4; ++t) o[t] = (f32x4){0.f, 0.f, 0.f, 0.f};
#pragma unroll
    for (int ks = 0; ks < 4; ++ks) {
      const int e = (ks * 32 + g * 8) ^ ((c & 7) << 3);  // matching swizzle
      const half8_t pf = *(const half8_t*)&Pl[w][c][e];
#pragma unroll
      for (int t = 0; t < 4; ++t) {
        const half8_t vf = *(const half8_t*)&VT[t * 16 + c][e];
        o[t] = __builtin_amdgcn_mfma_f32_16x16x32_f16(pf, vf, o[t], 0, 0, 0);
      }
    }
    // store (rows 4g+r, cols t*16+c), scaled by 1/rowsum
#pragma unroll
    for (int t = 0; t < 4; ++t)
#pragma unroll
      for (int r = 0; r < 4; ++r)
        Ob[(w * 32 + m * 16 + 4 * g + r) * DH + t * 16 + c] = o[t][r] * inv[r];
  }
}

extern "C" void kernel_launch(void* const* d_in, const int* in_sizes, int n_in,
                              void* d_out, int out_size, void* d_ws, size_t ws_size,
                              hipStream_t stream) {
  const float* q = (const float*)d_in[0];
  const float* k = (const float*)d_in[1];
  const float* v = (const float*)d_in[2];
  float* out = (float*)d_out;
  const int nballs = in_sizes[0] / (BS * DH);  // 4096
  ball_attn_kernel<<<dim3(nballs), dim3(256), 0, stream>>>(q, k, v, out);
}

// Round 6
// 137.847 us; speedup vs baseline: 4.7144x; 3.8467x over previous
//
#include <hip/hip_runtime.h>

typedef _Float16 half2_t __attribute__((ext_vector_type(2)));
typedef _Float16 half4_t __attribute__((ext_vector_type(4)));
typedef _Float16 half8_t __attribute__((ext_vector_type(8)));
typedef __fp16   fp16x2  __attribute__((ext_vector_type(2)));
typedef float    f32x4   __attribute__((ext_vector_type(4)));

#define BS 128
#define DH 64

__device__ __forceinline__ half2_t pkrtz(float x, float y) {
  fp16x2 t = __builtin_amdgcn_cvt_pkrtz(x, y);
  return __builtin_bit_cast(half2_t, t);
}

__device__ __forceinline__ half8_t cvt8(const float4 a, const float4 b) {
  half2_t h0 = pkrtz(a.x, a.y);
  half2_t h1 = pkrtz(a.z, a.w);
  half2_t h2 = pkrtz(b.x, b.y);
  half2_t h3 = pkrtz(b.z, b.w);
  half4_t lo = __builtin_shufflevector(h0, h1, 0, 1, 2, 3);
  half4_t hi = __builtin_shufflevector(h2, h3, 0, 1, 2, 3);
  return __builtin_shufflevector(lo, hi, 0, 1, 2, 3, 4, 5, 6, 7);
}

// (256,1): let the allocator follow demand (~115 regs). Forcing waves-per-EU
// caused catastrophic spills in R3-R5 (VGPR 48/64, ~1 GB scratch traffic).
__global__ __launch_bounds__(256, 1) void ball_attn_kernel(
    const float* __restrict__ Q, const float* __restrict__ Kk,
    const float* __restrict__ V, float* __restrict__ O) {
  // 16 KB + 16 KB = 32 KB, XOR-swizzled, no pad.
  __shared__ __align__(16) _Float16 VT[DH][BS];     // [d][key]
  __shared__ __align__(16) _Float16 Pl[4][16][BS];  // per-wave P half-tile (reused m=0,1)

  const int tid  = threadIdx.x;
  const int w    = tid >> 6;   // wave 0..3, owns q rows [32w, 32w+32)
  const int lane = tid & 63;
  const int c    = lane & 15;
  const int g    = lane >> 4;

  const size_t base = (size_t)blockIdx.x * (BS * DH);
  const float* Qb = Q + base;
  const float* Kb = Kk + base;
  const float* Vb = V + base;
  float*       Ob = O + base;

  // ---- stage V^T: streaming load->cvt->write (2 float4 live at a time) ----
  {
    const int kp0 = tid >> 4;        // 0..15
    const int d0  = (tid & 15) * 4;  // 0..60
#pragma unroll
    for (int it = 0; it < 4; ++it) {
      const int key0 = 2 * (it * 16 + kp0);
      const float4 a = *(const float4*)(Vb + (size_t)key0 * DH + d0);
      const float4 b = *(const float4*)(Vb + (size_t)(key0 + 1) * DH + d0);
      const float* ap = (const float*)&a;
      const float* bp = (const float*)&b;
#pragma unroll
      for (int j = 0; j < 4; ++j) {
        const int d = d0 + j;
        *(half2_t*)&VT[d][key0 ^ ((d & 7) << 3)] = pkrtz(ap[j], bp[j]);
      }
    }
  }

  // ---- Q fragments ----
  half8_t aq[2][2];
#pragma unroll
  for (int m = 0; m < 2; ++m)
#pragma unroll
    for (int ks = 0; ks < 2; ++ks) {
      const float* qp = Qb + (w * 32 + m * 16 + c) * DH + ks * 32 + g * 8;
      aq[m][ks] = cvt8(*(const float4*)qp, *(const float4*)(qp + 4));
    }

  __syncthreads();  // VT visible to all waves (only barrier in the kernel)

  // ---- QK^T for BOTH m-halves in one loop: bk lifetime = one iteration ----
  f32x4 acc[2][8];
#pragma unroll
  for (int m = 0; m < 2; ++m)
#pragma unroll
    for (int kt = 0; kt < 8; ++kt) acc[m][kt] = (f32x4){0.f, 0.f, 0.f, 0.f};

#pragma unroll
  for (int kt = 0; kt < 8; ++kt)
#pragma unroll
    for (int ks = 0; ks < 2; ++ks) {
      const float* kp = Kb + (kt * 16 + c) * DH + ks * 32 + g * 8;
      const half8_t bk = cvt8(*(const float4*)kp, *(const float4*)(kp + 4));
      acc[0][kt] = __builtin_amdgcn_mfma_f32_16x16x32_f16(aq[0][ks], bk, acc[0][kt], 0, 0, 0);
      acc[1][kt] = __builtin_amdgcn_mfma_f32_16x16x32_f16(aq[1][ks], bk, acc[1][kt], 0, 0, 0);
    }

  // ---- per 16-row half: softmax -> P|LDS -> PV -> store ----
#pragma unroll
  for (int m = 0; m < 2; ++m) {
    float mx[4], sm[4], inv[4];
#pragma unroll
    for (int r = 0; r < 4; ++r) {
      mx[r] = acc[m][0][r];
#pragma unroll
      for (int kt = 1; kt < 8; ++kt) mx[r] = fmaxf(mx[r], acc[m][kt][r]);
    }
#pragma unroll
    for (int r = 0; r < 4; ++r) {
      mx[r] = fmaxf(mx[r], __shfl_xor(mx[r], 1));
      mx[r] = fmaxf(mx[r], __shfl_xor(mx[r], 2));
      mx[r] = fmaxf(mx[r], __shfl_xor(mx[r], 4));
      mx[r] = fmaxf(mx[r], __shfl_xor(mx[r], 8));
      sm[r] = 0.f;
    }
#pragma unroll
    for (int kt = 0; kt < 8; ++kt)
#pragma unroll
      for (int r = 0; r < 4; ++r) {
        const float p = __expf((acc[m][kt][r] - mx[r]) * 0.125f);
        acc[m][kt][r] = p;
        sm[r] += p;
      }
#pragma unroll
    for (int r = 0; r < 4; ++r) {
      sm[r] += __shfl_xor(sm[r], 1);
      sm[r] += __shfl_xor(sm[r], 2);
      sm[r] += __shfl_xor(sm[r], 4);
      sm[r] += __shfl_xor(sm[r], 8);
      inv[r] = __builtin_amdgcn_rcpf(sm[r]);  // sum >= 1, safe
    }
    // write P (f16) swizzled; same-wave LDS ordering makes Pl[w] reuse safe
#pragma unroll
    for (int kt = 0; kt < 8; ++kt)
#pragma unroll
      for (int r = 0; r < 4; ++r) {
        const int row = 4 * g + r;
        Pl[w][row][(kt * 16 + c) ^ ((row & 7) << 3)] = (_Float16)acc[m][kt][r];
      }

    // PV: A = P row c (key-contig), B = VT row d (key-contig)
    f32x4 o[4];
#pragma unroll
    for (int t = 0; t < 4; ++t) o[t] = (f32x4){0.f, 0.f, 0.f, 0.f};
#pragma unroll
    for (int ks = 0; ks < 4; ++ks) {
      const int e = (ks * 32 + g * 8) ^ ((c & 7) << 3);  // matching swizzle
      const half8_t pf = *(const half8_t*)&Pl[w][c][e];
#pragma unroll
      for (int t = 0; t < 4; ++t) {
        const half8_t vf = *(const half8_t*)&VT[t * 16 + c][e];
        o[t] = __builtin_amdgcn_mfma_f32_16x16x32_f16(pf, vf, o[t], 0, 0, 0);
      }
    }
    // store (rows 4g+r, cols t*16+c), scaled by 1/rowsum
#pragma unroll
    for (int t = 0; t < 4; ++t)
#pragma unroll
      for (int r = 0; r < 4; ++r)
        Ob[(w * 32 + m * 16 + 4 * g + r) * DH + t * 16 + c] = o[t][r] * inv[r];
  }
}

extern "C" void kernel_launch(void* const* d_in, const int* in_sizes, int n_in,
                              void* d_out, int out_size, void* d_ws, size_t ws_size,
                              hipStream_t stream) {
  const float* q = (const float*)d_in[0];
  const float* k = (const float*)d_in[1];
  const float* v = (const float*)d_in[2];
  float* out = (float*)d_out;
  const int nballs = in_sizes[0] / (BS * DH);  // 4096
  ball_attn_kernel<<<dim3(nballs), dim3(256), 0, stream>>>(q, k, v, out);
}

// Round 7
// 115.030 us; speedup vs baseline: 5.6495x; 1.1984x over previous
//
#include <hip/hip_runtime.h>

typedef _Float16 half2_t __attribute__((ext_vector_type(2)));
typedef _Float16 half4_t __attribute__((ext_vector_type(4)));
typedef _Float16 half8_t __attribute__((ext_vector_type(8)));
typedef __fp16   fp16x2  __attribute__((ext_vector_type(2)));
typedef float    f32x4   __attribute__((ext_vector_type(4)));

#define BS 128
#define DH 64

__device__ __forceinline__ half2_t pkrtz(float x, float y) {
  fp16x2 t = __builtin_amdgcn_cvt_pkrtz(x, y);
  return __builtin_bit_cast(half2_t, t);
}

__device__ __forceinline__ half4_t cvt4(const float4 a) {
  half2_t h0 = pkrtz(a.x, a.y);
  half2_t h1 = pkrtz(a.z, a.w);
  return __builtin_shufflevector(h0, h1, 0, 1, 2, 3);
}

__device__ __forceinline__ half8_t cvt8(const float4 a, const float4 b) {
  half2_t h0 = pkrtz(a.x, a.y);
  half2_t h1 = pkrtz(a.z, a.w);
  half2_t h2 = pkrtz(b.x, b.y);
  half2_t h3 = pkrtz(b.z, b.w);
  half4_t lo = __builtin_shufflevector(h0, h1, 0, 1, 2, 3);
  half4_t hi = __builtin_shufflevector(h2, h3, 0, 1, 2, 3);
  return __builtin_shufflevector(lo, hi, 0, 1, 2, 3, 4, 5, 6, 7);
}

// (256,1): allocator follows demand (~115 regs). Forced waves-per-EU caps
// caused catastrophic spills in R3-R5.
__global__ __launch_bounds__(256, 1) void ball_attn_kernel(
    const float* __restrict__ Q, const float* __restrict__ Kk,
    const float* __restrict__ V, float* __restrict__ O) {
  // 48 KB total -> 3 blocks/CU. All tiles f16, XOR-swizzled, conflict-checked.
  __shared__ __align__(16) _Float16 Kh[BS * DH];      // [key][d], d ^= (key&7)<<3
  __shared__ __align__(16) _Float16 VT[DH * BS];      // [d][key], key ^= ((d>>2)&7)<<3
  __shared__ __align__(16) _Float16 Pl[4 * 16 * BS];  // per-wave P half (reused m=0,1)

  const int tid  = threadIdx.x;
  const int w    = tid >> 6;   // wave 0..3, owns q rows [32w, 32w+32)
  const int lane = tid & 63;
  const int c    = lane & 15;
  const int g    = lane >> 4;

  const size_t base = (size_t)blockIdx.x * (BS * DH);
  const float* Qb = Q + base;
  const float* Kb = Kk + base;
  const float* Vb = V + base;
  float*       Ob = O + base;

  // ---- STAGE K+V: issue all 16 coalesced float4 loads as ONE burst ----
  const int d0   = (tid & 15) * 4;  // 0..60
  const int kgrp = tid >> 4;        // 0..15
  float4 vA[4], vB[4], kA[4], kB[4];
#pragma unroll
  for (int it = 0; it < 4; ++it) {
    const int keyA = 2 * kgrp + 32 * it;
    vA[it] = *(const float4*)(Vb + (size_t)keyA * DH + d0);
    vB[it] = *(const float4*)(Vb + (size_t)(keyA + 1) * DH + d0);
    kA[it] = *(const float4*)(Kb + (size_t)keyA * DH + d0);
    kB[it] = *(const float4*)(Kb + (size_t)(keyA + 1) * DH + d0);
  }
  // convert + write (K: half4 row-major; V: half2 transposed)
#pragma unroll
  for (int it = 0; it < 4; ++it) {
    const int keyA = 2 * kgrp + 32 * it;
    *(half4_t*)&Kh[keyA * DH + (d0 ^ ((keyA & 7) << 3))]           = cvt4(kA[it]);
    *(half4_t*)&Kh[(keyA + 1) * DH + (d0 ^ (((keyA + 1) & 7) << 3))] = cvt4(kB[it]);
    const float* ap = (const float*)&vA[it];
    const float* bp = (const float*)&vB[it];
#pragma unroll
    for (int j = 0; j < 4; ++j) {
      const int d = d0 + j;
      *(half2_t*)&VT[d * BS + (keyA ^ (((d >> 2) & 7) << 3))] = pkrtz(ap[j], bp[j]);
    }
  }

  // ---- Q fragments (global -> reg, 4 loads) ----
  half8_t aq[2][2];
#pragma unroll
  for (int m = 0; m < 2; ++m)
#pragma unroll
    for (int ks = 0; ks < 2; ++ks) {
      const float* qp = Qb + (w * 32 + m * 16 + c) * DH + ks * 32 + g * 8;
      aq[m][ks] = cvt8(*(const float4*)qp, *(const float4*)(qp + 4));
    }

  __syncthreads();  // Kh+VT visible (only barrier in the kernel)

  // ---- QK^T for both m-halves; K from LDS (b128, swizzle-matched) ----
  f32x4 acc[2][8];
#pragma unroll
  for (int m = 0; m < 2; ++m)
#pragma unroll
    for (int kt = 0; kt < 8; ++kt) acc[m][kt] = (f32x4){0.f, 0.f, 0.f, 0.f};

#pragma unroll
  for (int kt = 0; kt < 8; ++kt)
#pragma unroll
    for (int ks = 0; ks < 2; ++ks) {
      const half8_t bk =
          *(const half8_t*)&Kh[(kt * 16 + c) * DH + ((ks * 32 + g * 8) ^ ((c & 7) << 3))];
      acc[0][kt] = __builtin_amdgcn_mfma_f32_16x16x32_f16(aq[0][ks], bk, acc[0][kt], 0, 0, 0);
      acc[1][kt] = __builtin_amdgcn_mfma_f32_16x16x32_f16(aq[1][ks], bk, acc[1][kt], 0, 0, 0);
    }

  // ---- per 16-row half: softmax -> P|LDS -> PV -> store ----
#pragma unroll
  for (int m = 0; m < 2; ++m) {
    float mx[4], sm[4], inv[4];
#pragma unroll
    for (int r = 0; r < 4; ++r) {
      mx[r] = acc[m][0][r];
#pragma unroll
      for (int kt = 1; kt < 8; ++kt) mx[r] = fmaxf(mx[r], acc[m][kt][r]);
    }
#pragma unroll
    for (int r = 0; r < 4; ++r) {
      mx[r] = fmaxf(mx[r], __shfl_xor(mx[r], 1));
      mx[r] = fmaxf(mx[r], __shfl_xor(mx[r], 2));
      mx[r] = fmaxf(mx[r], __shfl_xor(mx[r], 4));
      mx[r] = fmaxf(mx[r], __shfl_xor(mx[r], 8));
      sm[r] = 0.f;
    }
#pragma unroll
    for (int kt = 0; kt < 8; ++kt)
#pragma unroll
      for (int r = 0; r < 4; ++r) {
        const float p = __expf((acc[m][kt][r] - mx[r]) * 0.125f);
        acc[m][kt][r] = p;
        sm[r] += p;
      }
#pragma unroll
    for (int r = 0; r < 4; ++r) {
      sm[r] += __shfl_xor(sm[r], 1);
      sm[r] += __shfl_xor(sm[r], 2);
      sm[r] += __shfl_xor(sm[r], 4);
      sm[r] += __shfl_xor(sm[r], 8);
      inv[r] = __builtin_amdgcn_rcpf(sm[r]);  // sum >= 1, safe
    }
    // write P (f16) swizzled; same-wave LDS ordering makes Pl reuse safe
#pragma unroll
    for (int kt = 0; kt < 8; ++kt)
#pragma unroll
      for (int r = 0; r < 4; ++r) {
        const int row = 4 * g + r;
        Pl[(w * 16 + row) * BS + ((kt * 16 + c) ^ ((row & 7) << 3))] =
            (_Float16)acc[m][kt][r];
      }

    // PV: A = P row c (key-contig), B = VT row d (key-contig)
    f32x4 o[4];
#pragma unroll
    for (int t = 0; t < 4; ++t) o[t] = (f32x4){0.f, 0.f, 0.f, 0.f};
#pragma unroll
    for (int ks = 0; ks < 4; ++ks) {
      const int e0 = ks * 32 + g * 8;
      const half8_t pf = *(const half8_t*)&Pl[(w * 16 + c) * BS + (e0 ^ ((c & 7) << 3))];
#pragma unroll
      for (int t = 0; t < 4; ++t) {
        const int row = t * 16 + c;
        const half8_t vf = *(const half8_t*)&VT[row * BS + (e0 ^ (((row >> 2) & 7) << 3))];
        o[t] = __builtin_amdgcn_mfma_f32_16x16x32_f16(pf, vf, o[t], 0, 0, 0);
      }
    }
    // store (rows 4g+r, cols t*16+c), scaled by 1/rowsum
#pragma unroll
    for (int t = 0; t < 4; ++t)
#pragma unroll
      for (int r = 0; r < 4; ++r)
        Ob[(w * 32 + m * 16 + 4 * g + r) * DH + t * 16 + c] = o[t][r] * inv[r];
  }
}

extern "C" void kernel_launch(void* const* d_in, const int* in_sizes, int n_in,
                              void* d_out, int out_size, void* d_ws, size_t ws_size,
                              hipStream_t stream) {
  const float* q = (const float*)d_in[0];
  const float* k = (const float*)d_in[1];
  const float* v = (const float*)d_in[2];
  float* out = (float*)d_out;
  const int nballs = in_sizes[0] / (BS * DH);  // 4096
  ball_attn_kernel<<<dim3(nballs), dim3(256), 0, stream>>>(q, k, v, out);
}